// Round 5
// baseline (117.721 us; speedup 1.0000x reference)
//
#include <hip/hip_runtime.h>
#include <hip/hip_bf16.h>
#include <stdint.h>
#include <math.h>

#define D     256
#define NTOT  8192
#define NSRC  4096
#define NT    64                  // 64 tiles of 128 rows
#define NTRI  (NT * (NT + 1) / 2) // 2080 upper-tri tiles
#define PREPB 128                 // prep blocks (64 rows each)

using bf16x8 = __attribute__((ext_vector_type(8))) short;
using f32x4  = __attribute__((ext_vector_type(4))) float;

#if __has_builtin(__builtin_amdgcn_exp2f)
#define EXP2F __builtin_amdgcn_exp2f
#else
#define EXP2F exp2f
#endif

// Cross-block state in device globals: zeroed at module load; every kernel
// self-restores them to zero (last block resets after use) => state is
// identical at the start of every launch (graph-replay safe, poison-immune).
__device__ float        g_colsum[256];
__device__ float        g_Ssum;
__device__ unsigned int g_cnt0, g_cnt1;
__device__ float        g_cf;
__device__ float        g_part[NTRI];

// workspace layout (bytes) — xb/sq fully written before read each launch.
#define OFF_XB   ((size_t)0)                 // 4 MB bf16 X
#define OFF_SQ   ((size_t)NTOT * D * 2)      // 8192 f32 row sq-norms

// ---- prep: f32->bf16 roundtrip, row sq-norms; last block computes c4 ----
__global__ __launch_bounds__(256, 4) void prep_kernel(
    const float* __restrict__ src, const float* __restrict__ tgt,
    __hip_bfloat16* __restrict__ xb, float* __restrict__ sq)
{
  __shared__ float scol4[4][256];
  __shared__ float sSl[4];
  __shared__ int slast;
  const int tid = threadIdx.x, wave = tid >> 6, lane = tid & 63;
  const int row0 = blockIdx.x * 64 + wave * 16;   // blocks never straddle sides
  const float* p0 = (row0 < NSRC) ? (src + (size_t)row0 * D)
                                  : (tgt + (size_t)(row0 - NSRC) * D);
  float c0 = 0.f, c1 = 0.f, c2 = 0.f, c3 = 0.f, swave = 0.f;
  for (int rr = 0; rr < 16; ++rr) {
    const int row = row0 + rr;
    const float4 v = reinterpret_cast<const float4*>(p0 + (size_t)rr * D)[lane];
    const __hip_bfloat16 b0 = __float2bfloat16(v.x), b1 = __float2bfloat16(v.y),
                         b2 = __float2bfloat16(v.z), b3 = __float2bfloat16(v.w);
    ushort4 h;
    h.x = *(const unsigned short*)&b0; h.y = *(const unsigned short*)&b1;
    h.z = *(const unsigned short*)&b2; h.w = *(const unsigned short*)&b3;
    reinterpret_cast<ushort4*>(xb + (size_t)row * D)[lane] = h;
    const float f0 = __bfloat162float(b0), f1 = __bfloat162float(b1),
                f2 = __bfloat162float(b2), f3 = __bfloat162float(b3);
    c0 += f0; c1 += f1; c2 += f2; c3 += f3;
    float s = f0 * f0 + f1 * f1 + f2 * f2 + f3 * f3;
    #pragma unroll
    for (int off = 32; off > 0; off >>= 1) s += __shfl_down(s, off);
    if (lane == 0) { sq[row] = s; swave += s; }
  }
  scol4[wave][lane * 4 + 0] = c0;
  scol4[wave][lane * 4 + 1] = c1;
  scol4[wave][lane * 4 + 2] = c2;
  scol4[wave][lane * 4 + 3] = c3;
  if (lane == 0) sSl[wave] = swave;
  __syncthreads();
  // device-scope accumulation (low contention: 257 addresses x 128 blocks)
  atomicAdd(&g_colsum[tid],
            scol4[0][tid] + scol4[1][tid] + scol4[2][tid] + scol4[3][tid]);
  if (tid == 0) {
    atomicAdd(&g_Ssum, sSl[0] + sSl[1] + sSl[2] + sSl[3]);
    __threadfence();   // release: prior atomics/stores visible device-wide
    slast = (atomicAdd(&g_cnt0, 1u) == (unsigned)(PREPB - 1));
  }
  __syncthreads();
  if (slast) {
    const float cv = atomicExch(&g_colsum[tid], 0.f);  // coherent read + reset
    scol4[0][tid] = cv * cv;
    __syncthreads();
    for (int off = 128; off > 0; off >>= 1) {
      if (tid < off) scol4[0][tid] += scol4[0][tid + off];
      __syncthreads();
    }
    if (tid == 0) {
      const float S = atomicExch(&g_Ssum, 0.f);
      atomicExch(&g_cnt0, 0u);                         // restore for replay
      const double sumd2 = 2.0 * (double)NTOT * (double)S
                         - 2.0 * (double)scol4[0][0];
      const double bw = sumd2 / ((double)NTOT * (double)NTOT - (double)NTOT) / 4.0;
      g_cf = (float)(-1.4426950408889634 / (bw * 16.0)); // c4
    }
  }
}

// ---- main: triangular 128x128 tiles, reg-staged single-buffer LDS (4 blk/CU),
//      1-exp epilogue; last block reduces all tile partials -> out ----
__global__ __launch_bounds__(256, 4) void pair_kernel(
    const __hip_bfloat16* __restrict__ xb, const float* __restrict__ sq,
    float* __restrict__ out)
{
  const int idx = blockIdx.x;
  const float rr = sqrtf(4160.25f - 2.0f * (float)idx);
  int bi = (int)(64.5f - rr);
  while (NT * (bi + 1) - (bi + 1) * bi / 2 <= idx) ++bi;
  while (NT * bi - bi * (bi - 1) / 2 > idx) --bi;
  const int bj = bi + (idx - (NT * bi - bi * (bi - 1) / 2));

  __shared__ __align__(16) short lA[128 * 64];   // single-buffered: 16 KB
  __shared__ __align__(16) short lB[128 * 64];   // 16 KB
  __shared__ float sqA[128], sqB[128], wsum[4];
  __shared__ int slast;

  const int tid = threadIdx.x, wave = tid >> 6, lane = tid & 63;
  const int wr = wave >> 1, wc = wave & 1;

  const float c4 = g_cf;
  if (tid < 128) sqA[tid] = sq[bi * 128 + tid];
  else           sqB[tid - 128] = sq[bj * 128 + (tid - 128)];

  // Reg-staged swizzled LDS: LDS[row][c16 ^ ((row&7)<<4)] = G[row][c16].
  // Global load: row = base + wave*32 + q*8 + (lane>>3), col = (lane&7)*8 elems.
  // ds_write byte = row*128 + (((lane&7) ^ (lane>>3)) << 4)  (row&7 == lane>>3).
  const int lrow = lane >> 3, lcol = lane & 7;
  const int swz16 = ((lcol ^ lrow) << 4);
  const __hip_bfloat16* gA0 = xb + (size_t)(bi * 128 + wave * 32 + lrow) * D + lcol * 8;
  const __hip_bfloat16* gB0 = xb + (size_t)(bj * 128 + wave * 32 + lrow) * D + lcol * 8;
  char* wA0 = (char*)lA + (wave * 32 + lrow) * 128 + swz16;
  char* wB0 = (char*)lB + (wave * 32 + lrow) * 128 + swz16;

  int4 rA0, rA1, rA2, rA3, rB0, rB1, rB2, rB3;
#define LOADR(t) do {                                                       \
    rA0 = *(const int4*)(gA0 + (size_t)( 0) * D + (t) * 64);                \
    rA1 = *(const int4*)(gA0 + (size_t)( 8) * D + (t) * 64);                \
    rA2 = *(const int4*)(gA0 + (size_t)(16) * D + (t) * 64);                \
    rA3 = *(const int4*)(gA0 + (size_t)(24) * D + (t) * 64);                \
    rB0 = *(const int4*)(gB0 + (size_t)( 0) * D + (t) * 64);                \
    rB1 = *(const int4*)(gB0 + (size_t)( 8) * D + (t) * 64);                \
    rB2 = *(const int4*)(gB0 + (size_t)(16) * D + (t) * 64);                \
    rB3 = *(const int4*)(gB0 + (size_t)(24) * D + (t) * 64);                \
  } while (0)
#define WRITEL() do {                                                       \
    *(int4*)(wA0 +  0 * 128) = rA0;  *(int4*)(wA0 +  8 * 128) = rA1;        \
    *(int4*)(wA0 + 16 * 128) = rA2;  *(int4*)(wA0 + 24 * 128) = rA3;        \
    *(int4*)(wB0 +  0 * 128) = rB0;  *(int4*)(wB0 +  8 * 128) = rB1;        \
    *(int4*)(wB0 + 16 * 128) = rB2;  *(int4*)(wB0 + 24 * 128) = rB3;        \
  } while (0)

  f32x4 acc[4][4];
  #pragma unroll
  for (int mi = 0; mi < 4; ++mi)
    #pragma unroll
    for (int nj = 0; nj < 4; ++nj)
      acc[mi][nj] = (f32x4){0.f, 0.f, 0.f, 0.f};

  LOADR(0);
  WRITEL();
  __syncthreads();                       // tile 0 staged
  #pragma unroll
  for (int t = 0; t < 4; ++t) {
    if (t < 3) LOADR(t + 1);             // lands under this tile's compute
    #pragma unroll
    for (int ks = 0; ks < 2; ++ks) {
      bf16x8 af[4], bfr[4];
      const int kb = (ks * 32 + (lane >> 4) * 8) * 2;
      #pragma unroll
      for (int mi = 0; mi < 4; ++mi) {
        const int row = wr * 64 + mi * 16 + (lane & 15);
        af[mi] = *(const bf16x8*)((const char*)lA + row * 128 + (kb ^ ((row & 7) << 4)));
      }
      #pragma unroll
      for (int nj = 0; nj < 4; ++nj) {
        const int row = wc * 64 + nj * 16 + (lane & 15);
        bfr[nj] = *(const bf16x8*)((const char*)lB + row * 128 + (kb ^ ((row & 7) << 4)));
      }
      #pragma unroll
      for (int mi = 0; mi < 4; ++mi)
        #pragma unroll
        for (int nj = 0; nj < 4; ++nj)
          acc[mi][nj] = __builtin_amdgcn_mfma_f32_16x16x32_bf16(
              af[mi], bfr[nj], acc[mi][nj], 0, 0, 0);
    }
    if (t < 3) {
      __syncthreads();                   // all waves done reading tile t
      WRITEL();                          // overwrite with tile t+1
      __syncthreads();                   // tile t+1 staged
    }
  }
#undef LOADR
#undef WRITEL

  // epilogue: d2 = si + sj - 2*gram; e4 = exp2(d2*c4); e_{t-1} = e_t^2
  const int r0 = (lane >> 4) * 4, cc = lane & 15;
  float sjv[4];
  #pragma unroll
  for (int nj = 0; nj < 4; ++nj) sjv[nj] = sqB[wc * 64 + nj * 16 + cc];
  float tsum = 0.f;
  #pragma unroll
  for (int mi = 0; mi < 4; ++mi) {
    #pragma unroll
    for (int r = 0; r < 4; ++r) {
      const float si = sqA[wr * 64 + mi * 16 + r0 + r];
      #pragma unroll
      for (int nj = 0; nj < 4; ++nj) {
        float d2 = fmaf(-2.f, acc[mi][nj][r], si + sjv[nj]);
        d2 = fmaxf(d2, 0.f);
        const float e4 = EXP2F(d2 * c4);
        const float e3 = e4 * e4, e2 = e3 * e3;
        const float e1 = e2 * e2, e0 = e1 * e1;
        tsum += ((e4 + e3) + (e2 + e1)) + e0;
      }
    }
  }
  #pragma unroll
  for (int off = 32; off > 0; off >>= 1) tsum += __shfl_down(tsum, off);
  if (lane == 0) wsum[wave] = tsum;
  __syncthreads();
  if (tid == 0) {
    g_part[idx] = wsum[0] + wsum[1] + wsum[2] + wsum[3];
    __threadfence();                     // release part[idx]
    slast = (atomicAdd(&g_cnt1, 1u) == (unsigned)(NTRI - 1));
  }
  __syncthreads();
  if (slast) {
    // deterministic final reduce (reuse lA as f64 scratch: 6 KB <= 16 KB)
    double* red0 = (double*)lA;
    double* red1 = red0 + 256;
    double* red2 = red0 + 512;
    double a0 = 0.0, a1 = 0.0, a2 = 0.0;
    for (int j = tid; j < NTRI; j += 256) {
      const float v = atomicAdd(&g_part[j], 0.0f);   // coherent RMW read
      const float r1 = sqrtf(4160.25f - 2.0f * (float)j);
      int ti = (int)(64.5f - r1);
      while (NT * (ti + 1) - (ti + 1) * ti / 2 <= j) ++ti;
      while (NT * ti - ti * (ti - 1) / 2 > j) --ti;
      const int tj = ti + (j - (NT * ti - ti * (ti - 1) / 2));
      const double wv = ((ti == tj) ? 1.0 : 2.0) * (double)v;
      if (ti >= 32) a1 += wv;
      else if (tj >= 32) a2 += wv;
      else a0 += wv;
    }
    red0[tid] = a0; red1[tid] = a1; red2[tid] = a2;
    __syncthreads();
    for (int off = 128; off > 0; off >>= 1) {
      if (tid < off) {
        red0[tid] += red0[tid + off];
        red1[tid] += red1[tid + off];
        red2[tid] += red2[tid + off];
      }
      __syncthreads();
    }
    if (tid == 0) {
      out[0] = (float)((red0[0] + red1[0] - red2[0]) /
                       ((double)NSRC * (double)NSRC));
      atomicExch(&g_cnt1, 0u);                       // restore for replay
    }
  }
}

extern "C" void kernel_launch(void* const* d_in, const int* in_sizes, int n_in,
                              void* d_out, int out_size, void* d_ws, size_t ws_size,
                              hipStream_t stream) {
  (void)in_sizes; (void)n_in; (void)out_size; (void)ws_size;
  const float* src = (const float*)d_in[0];
  const float* tgt = (const float*)d_in[1];
  char* ws = (char*)d_ws;
  __hip_bfloat16* xb = (__hip_bfloat16*)(ws + OFF_XB);
  float* sq = (float*)(ws + OFF_SQ);

  prep_kernel<<<PREPB, 256, 0, stream>>>(src, tgt, xb, sq);
  pair_kernel<<<NTRI, 256, 0, stream>>>(xb, sq, (float*)d_out);
}

// Round 6
// 87.159 us; speedup vs baseline: 1.3506x; 1.3506x over previous
//
#include <hip/hip_runtime.h>
#include <hip/hip_bf16.h>
#include <stdint.h>
#include <math.h>

#define D     256
#define NTOT  8192
#define NSRC  4096
#define NT    64                  // 64 tiles of 128 rows
#define NTRI  (NT * (NT + 1) / 2) // 2080 upper-tri tiles
#define PREPB 256                 // prep blocks (32 rows each)
#define BK    32                  // K-step (halved: 33 KB LDS -> 3-4 blocks/CU)

using bf16x8 = __attribute__((ext_vector_type(8))) short;
using f32x4  = __attribute__((ext_vector_type(4))) float;

#define GLB_AS __attribute__((address_space(1)))
#define LDS_AS __attribute__((address_space(3)))

#if __has_builtin(__builtin_amdgcn_exp2f)
#define EXP2F __builtin_amdgcn_exp2f
#else
#define EXP2F exp2f
#endif

// Cross-block state in device globals: zeroed at module load; every launch
// self-restores to zero (last block resets after use) => replay-deterministic.
__device__ float        g_colsum[256];
__device__ float        g_Ssum;
__device__ unsigned int g_cnt0, g_cnt1;
__device__ float        g_cf;
__device__ float        g_part[NTRI];

// workspace: xb/sq fully written before read each launch (poison-safe).
#define OFF_XB   ((size_t)0)                 // 4 MB bf16 X
#define OFF_SQ   ((size_t)NTOT * D * 2)      // 8192 f32 row sq-norms

// ---- prep: f32->bf16 roundtrip, row sq-norms; last block computes c4 ----
__global__ __launch_bounds__(256) void prep_kernel(
    const float* __restrict__ src, const float* __restrict__ tgt,
    __hip_bfloat16* __restrict__ xb, float* __restrict__ sq)
{
  __shared__ float scol4[4][256];
  __shared__ float sSl[4];
  __shared__ int slast;
  const int tid = threadIdx.x, wave = tid >> 6, lane = tid & 63;
  const int row0 = blockIdx.x * 32 + wave * 8;    // blocks never straddle sides
  const float* p0 = (row0 < NSRC) ? (src + (size_t)row0 * D)
                                  : (tgt + (size_t)(row0 - NSRC) * D);
  float c0 = 0.f, c1 = 0.f, c2 = 0.f, c3 = 0.f, swave = 0.f;
  for (int rr = 0; rr < 8; ++rr) {
    const int row = row0 + rr;
    const float4 v = reinterpret_cast<const float4*>(p0 + (size_t)rr * D)[lane];
    const __hip_bfloat16 b0 = __float2bfloat16(v.x), b1 = __float2bfloat16(v.y),
                         b2 = __float2bfloat16(v.z), b3 = __float2bfloat16(v.w);
    ushort4 h;
    h.x = *(const unsigned short*)&b0; h.y = *(const unsigned short*)&b1;
    h.z = *(const unsigned short*)&b2; h.w = *(const unsigned short*)&b3;
    reinterpret_cast<ushort4*>(xb + (size_t)row * D)[lane] = h;
    const float f0 = __bfloat162float(b0), f1 = __bfloat162float(b1),
                f2 = __bfloat162float(b2), f3 = __bfloat162float(b3);
    c0 += f0; c1 += f1; c2 += f2; c3 += f3;
    float s = f0 * f0 + f1 * f1 + f2 * f2 + f3 * f3;
    #pragma unroll
    for (int off = 32; off > 0; off >>= 1) s += __shfl_down(s, off);
    if (lane == 0) { sq[row] = s; swave += s; }
  }
  scol4[wave][lane * 4 + 0] = c0;
  scol4[wave][lane * 4 + 1] = c1;
  scol4[wave][lane * 4 + 2] = c2;
  scol4[wave][lane * 4 + 3] = c3;
  if (lane == 0) sSl[wave] = swave;
  __syncthreads();
  atomicAdd(&g_colsum[tid],
            scol4[0][tid] + scol4[1][tid] + scol4[2][tid] + scol4[3][tid]);
  if (tid == 0) {
    atomicAdd(&g_Ssum, sSl[0] + sSl[1] + sSl[2] + sSl[3]);
    __threadfence();
    slast = (atomicAdd(&g_cnt0, 1u) == (unsigned)(PREPB - 1));
  }
  __syncthreads();
  if (slast) {
    const float cv = atomicExch(&g_colsum[tid], 0.f);  // coherent read + reset
    scol4[0][tid] = cv * cv;
    __syncthreads();
    for (int off = 128; off > 0; off >>= 1) {
      if (tid < off) scol4[0][tid] += scol4[0][tid + off];
      __syncthreads();
    }
    if (tid == 0) {
      const float S = atomicExch(&g_Ssum, 0.f);
      atomicExch(&g_cnt0, 0u);
      const double sumd2 = 2.0 * (double)NTOT * (double)S
                         - 2.0 * (double)scol4[0][0];
      const double bw = sumd2 / ((double)NTOT * (double)NTOT - (double)NTOT) / 4.0;
      g_cf = (float)(-1.4426950408889634 / (bw * 16.0)); // c4
    }
  }
}

// ---- main: triangular 128x128 tiles, BK=32 gload_lds double-buffer,
//      counted vmcnt, setprio'd MFMA, 1-exp epilogue; last block -> out ----
__global__ __launch_bounds__(256) void pair_kernel(
    const __hip_bfloat16* __restrict__ xb, const float* __restrict__ sq,
    float* __restrict__ out)
{
  const int idx = blockIdx.x;
  const float rr = sqrtf(4160.25f - 2.0f * (float)idx);
  int bi = (int)(64.5f - rr);
  while (NT * (bi + 1) - (bi + 1) * bi / 2 <= idx) ++bi;
  while (NT * bi - bi * (bi - 1) / 2 > idx) --bi;
  const int bj = bi + (idx - (NT * bi - bi * (bi - 1) / 2));

  __shared__ __align__(16) short lA[2][128 * BK];   // 2 x 8 KB
  __shared__ __align__(16) short lB[2][128 * BK];   // 2 x 8 KB
  __shared__ float sqA[128], sqB[128], wsum[4];
  __shared__ int slast;

  const int tid = threadIdx.x, wave = tid >> 6, lane = tid & 63;
  const int wr = wave >> 1, wc = wave & 1;

  const float c4 = g_cf;
  if (tid < 128) sqA[tid] = sq[bi * 128 + tid];
  else           sqB[tid - 128] = sq[bj * 128 + (tid - 128)];

  // 64B rows: swizzle byte ^= ((row>>1)&3)<<4. gload_lds writes linear
  // (wave base + lane*16): lane l covers row l>>2, slot l&3, so the
  // pre-swizzled GLOBAL source elem-col is ((l&3) ^ ((l>>3)&3))*8
  // (rule 21: inverse-swz source + swz read; XOR is an involution).
  const int srow = lane >> 2;                                 // 0..15
  const int sel  = ((lane & 3) ^ ((lane >> 3) & 3)) * 8;      // source elem col
  const __hip_bfloat16* gA0 = xb + (size_t)(bi * 128 + wave * 32 + srow) * D + sel;
  const __hip_bfloat16* gB0 = xb + (size_t)(bj * 128 + wave * 32 + srow) * D + sel;

  f32x4 acc[4][4];
  #pragma unroll
  for (int mi = 0; mi < 4; ++mi)
    #pragma unroll
    for (int nj = 0; nj < 4; ++nj)
      acc[mi][nj] = (f32x4){0.f, 0.f, 0.f, 0.f};

#define STAGE(buf, t) do {                                                   \
    char* dA_ = (char*)lA[buf] + (wave * 32) * 64;                           \
    char* dB_ = (char*)lB[buf] + (wave * 32) * 64;                           \
    _Pragma("unroll")                                                        \
    for (int q = 0; q < 2; ++q) {                                            \
      __builtin_amdgcn_global_load_lds(                                      \
          (const GLB_AS uint32_t*)(gA0 + (size_t)q * 16 * D + (t) * BK),     \
          (LDS_AS uint32_t*)(dA_ + q * 16 * 64), 16, 0, 0);                  \
      __builtin_amdgcn_global_load_lds(                                      \
          (const GLB_AS uint32_t*)(gB0 + (size_t)q * 16 * D + (t) * BK),     \
          (LDS_AS uint32_t*)(dB_ + q * 16 * 64), 16, 0, 0);                  \
    } } while (0)

  // fragment-read swizzle: byte = row*64 + ((k_slot ^ ((row>>1)&3))<<4),
  // k_slot = lane>>4; (row>>1)&3 == (lane>>1)&3 (row ≡ lane&15 mod 8-group)
  const int kswz = ((((lane >> 4) & 3) ^ ((lane >> 1) & 3)) << 4);
  const int rbyteA = wr * 64 * 64 + (lane & 15) * 64 + kswz;
  const int rbyteB = wc * 64 * 64 + (lane & 15) * 64 + kswz;

  STAGE(0, 0);   // 4 loads in flight
  #pragma unroll
  for (int t = 0; t < 8; ++t) {
    // issue next tile BEFORE this tile's wait: counted vmcnt keeps the next
    // tile's 4 loads in flight across the barrier (never a full drain)
    if (t < 7) STAGE((t + 1) & 1, t + 1);
    __builtin_amdgcn_sched_barrier(0);
    if (t < 7)  asm volatile("s_waitcnt vmcnt(4)" ::: "memory");
    else        asm volatile("s_waitcnt vmcnt(0)" ::: "memory");
    __builtin_amdgcn_s_barrier();          // all waves: tile-t data resident
    __builtin_amdgcn_sched_barrier(0);

    const char* bufA = (const char*)lA[t & 1];
    const char* bufB = (const char*)lB[t & 1];
    bf16x8 af[4], bfr[4];
    #pragma unroll
    for (int mi = 0; mi < 4; ++mi)
      af[mi] = *(const bf16x8*)(bufA + rbyteA + mi * 1024);
    #pragma unroll
    for (int nj = 0; nj < 4; ++nj)
      bfr[nj] = *(const bf16x8*)(bufB + rbyteB + nj * 1024);
    __builtin_amdgcn_s_setprio(1);
    #pragma unroll
    for (int mi = 0; mi < 4; ++mi)
      #pragma unroll
      for (int nj = 0; nj < 4; ++nj)
        acc[mi][nj] = __builtin_amdgcn_mfma_f32_16x16x32_bf16(
            af[mi], bfr[nj], acc[mi][nj], 0, 0, 0);
    __builtin_amdgcn_s_setprio(0);
    if (t < 7) {
      __builtin_amdgcn_sched_barrier(0);
      __builtin_amdgcn_s_barrier();        // readers of buf[t&1] done
      __builtin_amdgcn_sched_barrier(0);   // before STAGE overwrites it
    }
  }
#undef STAGE

  // epilogue: d2 = si + sj - 2*gram; e4 = exp2(d2*c4); e_{t-1} = e_t^2
  const int r0 = (lane >> 4) * 4, cc = lane & 15;
  float sjv[4];
  #pragma unroll
  for (int nj = 0; nj < 4; ++nj) sjv[nj] = sqB[wc * 64 + nj * 16 + cc];
  float tsum = 0.f;
  #pragma unroll
  for (int mi = 0; mi < 4; ++mi) {
    #pragma unroll
    for (int r = 0; r < 4; ++r) {
      const float si = sqA[wr * 64 + mi * 16 + r0 + r];
      #pragma unroll
      for (int nj = 0; nj < 4; ++nj) {
        float d2 = fmaf(-2.f, acc[mi][nj][r], si + sjv[nj]);
        d2 = fmaxf(d2, 0.f);
        const float e4 = EXP2F(d2 * c4);
        const float e3 = e4 * e4, e2 = e3 * e3;
        const float e1 = e2 * e2, e0 = e1 * e1;
        tsum += ((e4 + e3) + (e2 + e1)) + e0;
      }
    }
  }
  #pragma unroll
  for (int off = 32; off > 0; off >>= 1) tsum += __shfl_down(tsum, off);
  if (lane == 0) wsum[wave] = tsum;
  __syncthreads();
  if (tid == 0) {
    g_part[idx] = wsum[0] + wsum[1] + wsum[2] + wsum[3];
    __threadfence();
    slast = (atomicAdd(&g_cnt1, 1u) == (unsigned)(NTRI - 1));
  }
  __syncthreads();
  if (slast) {
    double* red0 = (double*)lA;            // 6 KB scratch in 16 KB lA
    double* red1 = red0 + 256;
    double* red2 = red0 + 512;
    double a0 = 0.0, a1 = 0.0, a2 = 0.0;
    for (int j = tid; j < NTRI; j += 256) {
      const float v = atomicAdd(&g_part[j], 0.0f);   // coherent RMW read
      const float r1 = sqrtf(4160.25f - 2.0f * (float)j);
      int ti = (int)(64.5f - r1);
      while (NT * (ti + 1) - (ti + 1) * ti / 2 <= j) ++ti;
      while (NT * ti - ti * (ti - 1) / 2 > j) --ti;
      const int tj = ti + (j - (NT * ti - ti * (ti - 1) / 2));
      const double wv = ((ti == tj) ? 1.0 : 2.0) * (double)v;
      if (ti >= 32) a1 += wv;
      else if (tj >= 32) a2 += wv;
      else a0 += wv;
    }
    red0[tid] = a0; red1[tid] = a1; red2[tid] = a2;
    __syncthreads();
    for (int off = 128; off > 0; off >>= 1) {
      if (tid < off) {
        red0[tid] += red0[tid + off];
        red1[tid] += red1[tid + off];
        red2[tid] += red2[tid + off];
      }
      __syncthreads();
    }
    if (tid == 0) {
      out[0] = (float)((red0[0] + red1[0] - red2[0]) /
                       ((double)NSRC * (double)NSRC));
      atomicExch(&g_cnt1, 0u);
    }
  }
}

extern "C" void kernel_launch(void* const* d_in, const int* in_sizes, int n_in,
                              void* d_out, int out_size, void* d_ws, size_t ws_size,
                              hipStream_t stream) {
  (void)in_sizes; (void)n_in; (void)out_size; (void)ws_size;
  const float* src = (const float*)d_in[0];
  const float* tgt = (const float*)d_in[1];
  char* ws = (char*)d_ws;
  __hip_bfloat16* xb = (__hip_bfloat16*)(ws + OFF_XB);
  float* sq = (float*)(ws + OFF_SQ);

  prep_kernel<<<PREPB, 256, 0, stream>>>(src, tgt, xb, sq);
  pair_kernel<<<NTRI, 256, 0, stream>>>(xb, sq, (float*)d_out);
}